// Round 7
// baseline (1046.619 us; speedup 1.0000x reference)
//
#include <hip/hip_runtime.h>

#define TPB  448   // 7 waves: wave w owns 16-col group w (cols 0..111; H=100 real)
#define ROWS 4     // batch rows per block -> 512 blocks -> 2 co-resident blocks/CU

typedef __attribute__((ext_vector_type(8))) short bf16x8;
typedef __attribute__((ext_vector_type(4))) float f32x4;

// round-to-nearest-even fp32 -> bf16 (as raw short)
__device__ __forceinline__ short f2bf(float f) {
    union { float f; unsigned u; } v; v.f = f;
    unsigned r = (v.u + 0x7FFFu + ((v.u >> 16) & 1u)) >> 16;
    return (short)r;
}

__device__ __forceinline__ float frcp(float x) {
#if __has_builtin(__builtin_amdgcn_rcpf)
    return __builtin_amdgcn_rcpf(x);
#else
    return 1.0f / x;
#endif
}

__device__ __forceinline__ float fast_sig(float x) {
    return frcp(1.0f + __expf(-x));
}
__device__ __forceinline__ float fast_tanh(float x) {
    return 1.0f - 2.0f * frcp(1.0f + __expf(2.0f * x));
}

// lanes 0-31 keep a; lanes 32-63 receive b[lane-32].
__device__ __forceinline__ float permlane_pack(float a, float b) {
#if __has_builtin(__builtin_amdgcn_permlane32_swap)
    auto r = __builtin_amdgcn_permlane32_swap(__float_as_int(a), __float_as_int(b),
                                              false, false);
    return __int_as_float(r[0]);
#else
    const int l  = (int)(threadIdx.x & 63);
    const int bs = __shfl(__float_as_int(b), l ^ 32, 64);
    return __int_as_float(l >= 32 ? bs : __float_as_int(a));
#endif
}

// Barrier that only drains LDS traffic: x prefetch loads and out stores stay
// in flight across it (no vmcnt(0) drain -> no exposed HBM latency per step).
__device__ __forceinline__ void block_sync_lds() {
    asm volatile("s_waitcnt lgkmcnt(0)\n\ts_barrier" ::: "memory");
}

// ---------------------------------------------------------------------------
// Fused LSTM, software-pipelined one step ahead on the x@Wi product.
// ROWS=4 batch rows/block, 512 blocks -> 2 independent blocks co-resident per
// CU (VGPR 128 => 16 waves/CU; LDS 2x22KB): while one block waits at its
// barrier / in MFMA+LDS latency, the other's waves issue -> latency hiding
// across independent recurrences.
//   critical segment per step: barrier -> ds_read aH -> 16 Wh-MFMA (2 depth-2
//   chains) -> z = accI + zH -> permlane -> gates -> h ds_write
//   shadow (overlaps barrier wait): accI(t+1) = bh + x(t+1)@Wi (16 MFMA),
//   out_{t-1} = relu(h(t-1)@Wd + bd), x staging + prefetch.
// xA triple-buffered (pre-barrier writer vs post-barrier reader, 1-gen skew).
// hA rows ROWS..15 are never written (stay zero): padding rows produce no
// stores and contaminate nothing (MFMA rows are independent).
// ---------------------------------------------------------------------------
__global__ __launch_bounds__(TPB, 2) void lstm_fused_all(
    const float* __restrict__ x,   // [2048,250,128]
    const float* __restrict__ Wi,  // [128,400]
    const float* __restrict__ Wh,  // [100,400]
    const float* __restrict__ bh,  // [400]
    const float* __restrict__ Wd,  // [100,100]
    const float* __restrict__ bd,  // [100]
    float* __restrict__ out)       // [2048,250,100]
{
    const int tid  = threadIdx.x;
    const int lane = tid & 63;
    const int wave = tid >> 6;    // 0..6, also the col group
    const int m16  = lane & 15;
    const int kg   = lane >> 4;   // k-group 0..3 (MFMA fragment index)
    const int b0   = blockIdx.x * ROWS;

    __shared__ short xA[3][16 * 136];  // x bf16 A-layout, TRIPLE buffered
    __shared__ short hA[2][16 * 136];  // h bf16 A-layout, double buffered

    for (int i = tid; i < 3 * 16 * 136; i += TPB) ((short*)xA)[i] = 0;
    for (int i = tid; i < 2 * 16 * 136; i += TPB) ((short*)hA)[i] = 0;

    const int  cg    = wave * 16 + m16;   // col within H-padded 112
    const bool valid = (cg < 100);

    // ---- preload fragments: Wi/Wh for all 4 gates of col group `wave`, Wd ----
    bf16x8 bWi[4][4], bWh[4][4], bWd[4];
    float  bhv[4];
    #pragma unroll
    for (int G = 0; G < 4; ++G) {
        const int c = G * 100 + cg;
        bhv[G] = valid ? bh[c] : 0.0f;
        #pragma unroll
        for (int s = 0; s < 4; ++s) {
            bf16x8 vi, vh;
            #pragma unroll
            for (int j = 0; j < 8; ++j) {
                const int k = s * 32 + kg * 8 + j;
                vi[j] = f2bf(valid ? Wi[k * 400 + c] : 0.0f);               // K=128 exact
                vh[j] = f2bf((valid && k < 100) ? Wh[k * 400 + c] : 0.0f);  // K pad
            }
            bWi[G][s] = vi;
            bWh[G][s] = vh;
        }
    }
    const float bdv = valid ? bd[cg] : 0.0f;
    #pragma unroll
    for (int s = 0; s < 4; ++s) {
        bf16x8 vd;
        #pragma unroll
        for (int j = 0; j < 8; ++j) {
            const int k = s * 32 + kg * 8 + j;
            vd[j] = f2bf((valid && k < 100) ? Wd[k * 100 + cg] : 0.0f);
        }
        bWd[s] = vd;
    }

    // row ownership for gates/out: 2 rows per lane over all 64 lanes
    const int  kgq     = (lane >> 4) & 1;                    // 0,1
    const int  rowbase = kgq * 4 + ((lane >= 32) ? 2 : 0);   // rows {rowbase, rowbase+1}
    const bool rowv    = (rowbase < ROWS);                   // real batch rows only
    float myC[2] = {0.f, 0.f};
    long  ob2[2];
    #pragma unroll
    for (int j = 0; j < 2; ++j)
        ob2[j] = (long)(b0 + (rowv ? rowbase + j : 0)) * 25000 + cg;  // + (t-1)*100 at store

    // x prefetch, depth 2: la = x(t+1) at loop top, lb = x(t+2).
    // waves 0..ROWS-1 stage row `wave`; other waves do no x work.
    const bool stager = (wave < ROWS);
    const long xb0 = ((long)(b0 + (stager ? wave : 0)) * 250) * 128 + lane * 2;
    float2 la0 = {0.f, 0.f}, lb0 = {0.f, 0.f};
    if (stager) {
        la0 = *(const float2*)&x[xb0];          // x(0)
        lb0 = *(const float2*)&x[xb0 + 128];    // x(1)
    }

    const int aoff = m16 * 136 + kg * 8;

    __syncthreads();   // LDS zeros visible

    // ---- prologue: stage x(0) into xA[0]; accI(0) = bh + x(0)@Wi ----
    if (stager) {
        short2 s0; s0.x = f2bf(la0.x); s0.y = f2bf(la0.y);
        *(short2*)&xA[0][wave * 136 + lane * 2] = s0;
    }
    __syncthreads();   // x(0) visible
    if (stager) {
        la0 = lb0;                                  // la = x(1)
        lb0 = *(const float2*)&x[xb0 + 2 * 128];    // lb = x(2)
    }

    f32x4 accI[4];
    {
        bf16x8 aX[4];
        #pragma unroll
        for (int s = 0; s < 4; ++s)
            aX[s] = *(const bf16x8*)&xA[0][aoff + s * 32];
        #pragma unroll
        for (int G = 0; G < 4; ++G) {
            const f32x4 a = {bhv[G], bhv[G], bhv[G], bhv[G]};
            accI[G] = a;
        }
        #pragma unroll
        for (int s = 0; s < 4; ++s)
            #pragma unroll
            for (int G = 0; G < 4; ++G)
                accI[G] = __builtin_amdgcn_mfma_f32_16x16x32_bf16(aX[s], bWi[G][s], accI[G], 0, 0, 0);
    }

    int  bufx = 1;        // (t+1)%3 rotation
    int  ooff = 0;        // (t-1)*100 at out-store time
    long xoff = 3 * 128;  // (t+3)*128 for the lb load

    #pragma unroll 1
    for (int t = 0; t <= 250; ++t) {
        const int bufh = t & 1;

        // stage x(t+1) pre-barrier (triple buffer: race-free vs t-1 readers)
        if (stager && t + 1 < 250) {
            short2 s0; s0.x = f2bf(la0.x); s0.y = f2bf(la0.y);
            *(short2*)&xA[bufx][wave * 136 + lane * 2] = s0;
        }
        block_sync_lds();  // x(t+1) + h(t-1) ds_writes visible; vmem in flight

        // rotate prefetch; issue next load after the barrier
        if (stager) {
            if (t + 1 < 250) la0 = lb0;
            if (t + 3 < 250) lb0 = *(const float2*)&x[xb0 + xoff];
        }
        xoff += 128;

        // h(t-1) fragments — z-GEMM (critical) and out-GEMM (shadow)
        bf16x8 aH[4];
        #pragma unroll
        for (int s = 0; s < 4; ++s)
            aH[s] = *(const bf16x8*)&hA[bufh][aoff + s * 32];

        // ---- CRITICAL: z(t) = accI(t) + h(t-1)@Wh -> gates -> c,h ----
        if (t < 250) {
            f32x4 accH0[4], accH1[4];
            #pragma unroll
            for (int G = 0; G < 4; ++G) {
                const f32x4 zz = {0.f, 0.f, 0.f, 0.f};
                accH0[G] = __builtin_amdgcn_mfma_f32_16x16x32_bf16(aH[0], bWh[G][0], zz, 0, 0, 0);
                accH1[G] = __builtin_amdgcn_mfma_f32_16x16x32_bf16(aH[2], bWh[G][2], zz, 0, 0, 0);
            }
            #pragma unroll
            for (int G = 0; G < 4; ++G) {
                accH0[G] = __builtin_amdgcn_mfma_f32_16x16x32_bf16(aH[1], bWh[G][1], accH0[G], 0, 0, 0);
                accH1[G] = __builtin_amdgcn_mfma_f32_16x16x32_bf16(aH[3], bWh[G][3], accH1[G], 0, 0, 0);
            }

            float z0[4], z1[4];
            #pragma unroll
            for (int G = 0; G < 4; ++G) {
                const f32x4 zs = accI[G] + (accH0[G] + accH1[G]);
                z0[G] = permlane_pack(zs[0], zs[2]);
                z1[G] = permlane_pack(zs[1], zs[3]);
            }
            if (valid && rowv) {
                {
                    const float ig = fast_sig(z0[0]);
                    const float fg = fast_sig(z0[1]);
                    const float gg = fast_tanh(z0[2]);
                    const float og = fast_sig(z0[3]);
                    const float cs = fg * myC[0] + ig * gg;
                    myC[0] = cs;
                    const float h = og * fast_tanh(cs);
                    hA[bufh ^ 1][(rowbase + 0) * 136 + cg] = f2bf(h);
                }
                {
                    const float ig = fast_sig(z1[0]);
                    const float fg = fast_sig(z1[1]);
                    const float gg = fast_tanh(z1[2]);
                    const float og = fast_sig(z1[3]);
                    const float cs = fg * myC[1] + ig * gg;
                    myC[1] = cs;
                    const float h = og * fast_tanh(cs);
                    hA[bufh ^ 1][(rowbase + 1) * 136 + cg] = f2bf(h);
                }
            }
        }

        // ---- SHADOW 1: accI(t+1) = bh + x(t+1)@Wi (overlaps barrier wait) ----
        if (t + 1 < 250) {
            bf16x8 aX[4];
            #pragma unroll
            for (int s = 0; s < 4; ++s)
                aX[s] = *(const bf16x8*)&xA[bufx][aoff + s * 32];
            #pragma unroll
            for (int G = 0; G < 4; ++G) {
                const f32x4 a = {bhv[G], bhv[G], bhv[G], bhv[G]};
                accI[G] = a;
            }
            #pragma unroll
            for (int s = 0; s < 4; ++s)
                #pragma unroll
                for (int G = 0; G < 4; ++G)
                    accI[G] = __builtin_amdgcn_mfma_f32_16x16x32_bf16(aX[s], bWi[G][s], accI[G], 0, 0, 0);
            bufx = (bufx == 2) ? 0 : bufx + 1;
        }

        // ---- SHADOW 2: out_{t-1} = relu(h(t-1)@Wd + bd) ----
        if (t > 0) {
            f32x4 oacc = {bdv, bdv, bdv, bdv};
            #pragma unroll
            for (int s = 0; s < 4; ++s)
                oacc = __builtin_amdgcn_mfma_f32_16x16x32_bf16(aH[s], bWd[s], oacc, 0, 0, 0);
            const float o0 = permlane_pack(oacc[0], oacc[2]);
            const float o1 = permlane_pack(oacc[1], oacc[3]);
            if (valid && rowv) {
                out[ob2[0] + ooff] = o0 > 0.0f ? o0 : 0.0f;
                out[ob2[1] + ooff] = o1 > 0.0f ? o1 : 0.0f;
            }
            ooff += 100;
        }
    }
}

extern "C" void kernel_launch(void* const* d_in, const int* in_sizes, int n_in,
                              void* d_out, int out_size, void* d_ws, size_t ws_size,
                              hipStream_t stream) {
    (void)in_sizes; (void)n_in; (void)out_size; (void)d_ws; (void)ws_size;
    const float* x  = (const float*)d_in[0];
    const float* Wi = (const float*)d_in[1];
    const float* Wh = (const float*)d_in[2];
    const float* bh = (const float*)d_in[3];
    const float* Wd = (const float*)d_in[4];
    const float* bd = (const float*)d_in[5];
    float* out = (float*)d_out;

    lstm_fused_all<<<2048 / ROWS, TPB, 0, stream>>>(x, Wi, Wh, bh, Wd, bd, out);
}